// Round 9
// baseline (201.650 us; speedup 1.0000x reference)
//
#include <hip/hip_runtime.h>

// EGNN layer, round 17: leave node_k at its proven 61 us (issue-bound floor
// for this structure; r16 confirmed no latency component). Attack the other
// 133 us: (a) mlp_fused USE_HB path reads A (hb/dh bf16) and B (weights,
// L2-resident) fragments DIRECTLY from global — no As/Bs LDS staging, zero
// __syncthreads (Ts is per-wave-private banding), 3 blocks/CU. (b) scatter
// fused into the pgemm launch (independent work, hides ~10 us + one gap).
// B=4, N=16384, E=65536, DH=128, DM=64.  NB = 65536 global nodes.

typedef unsigned short ushort_t;
typedef __attribute__((ext_vector_type(8))) short bf16x8;
typedef __attribute__((ext_vector_type(4))) float f32x4;
typedef _Float16 h2 __attribute__((ext_vector_type(2)));

__device__ __forceinline__ float fast_rcp(float v) { return __builtin_amdgcn_rcpf(v); }
__device__ __forceinline__ float fast_silu(float v) { return v * fast_rcp(1.0f + __expf(-v)); }
__device__ __forceinline__ ushort_t f2bf(float f) {
    unsigned u = __float_as_uint(f);
    u += 0x7fffu + ((u >> 16) & 1u);
    return (ushort_t)(u >> 16);
}
__device__ __forceinline__ float bf2f(ushort_t b) {
    return __uint_as_float(((unsigned)b) << 16);
}
__device__ __forceinline__ h2 u2h2(unsigned u) {
    union { unsigned u; h2 h; } v; v.u = u; return v.h;
}

// ---------------------------------------------------------------------------
// init: cursor=0 (65536) + weight transforms. 488*256 = 124928 threads exact.
//  W1t  bf16[128][128] : fused pe_w1 cols, k-contiguous
//  Wp1t bf16[128][192] : ph_w1^T
//  Wp2t bf16[128][128] : ph_w2^T
//  w2h  uint[32][64]   : w2h[k2*64+c] = half2(pe_w2[2k2][c], pe_w2[2k2+1][c])
// ---------------------------------------------------------------------------
__global__ __launch_bounds__(256) void init_k(const float* __restrict__ pe_w1,
                                              const float* __restrict__ pe_w2,
                                              const float* __restrict__ ph_w1,
                                              const float* __restrict__ ph_w2,
                                              int* __restrict__ cursor,
                                              ushort_t* __restrict__ W1t,
                                              ushort_t* __restrict__ Wp1t,
                                              ushort_t* __restrict__ Wp2t,
                                              unsigned* __restrict__ w2h) {
    int gg = blockIdx.x * 256 + threadIdx.x;
    if (gg < 65536) { cursor[gg] = 0; return; }
    int g = gg - 65536;
    if (g < 16384) {
        int c = g >> 7, k = g & 127;
        float v = (c < 64) ? pe_w1[k * 64 + c] : pe_w1[(128 + k) * 64 + (c - 64)];
        W1t[g] = f2bf(v);
    } else if (g < 40960) {
        int g2 = g - 16384;
        int n = g2 / 192, k = g2 - n * 192;
        Wp1t[g2] = f2bf(ph_w1[k * 128 + n]);
    } else if (g < 57344) {
        int g3 = g - 40960;
        int n = g3 >> 7, k = g3 & 127;
        Wp2t[g3] = f2bf(ph_w2[k * 128 + n]);
    } else if (g < 59392) {
        int g4 = g - 57344;
        int k2 = g4 >> 6, c = g4 & 63;
        union { unsigned u; _Float16 h[2]; } p;
        p.h[0] = (_Float16)pe_w2[(2 * k2) * 64 + c];
        p.h[1] = (_Float16)pe_w2[(2 * k2 + 1) * 64 + c];
        w2h[g4] = p.u;
    }
}

// ---------------------------------------------------------------------------
// pgemm (blocks 0..511) + scatter (blocks 512..1535), fused launch.
// pgemm: P = h @ [W1_top|W1_mid] (bf16 out), emits hb=bf16(h) when EMIT.
// scatter: elist[gi*64 + slot] = gj (independent of pgemm; overlaps).
// ---------------------------------------------------------------------------
template <bool EMIT_BF16>
__global__ __launch_bounds__(256, 2) void pgemm_scatter_k(const float* __restrict__ A0,
                                                          const ushort_t* __restrict__ Wt,
                                                          ushort_t* __restrict__ outP,
                                                          ushort_t* __restrict__ hbout,
                                                          const int* __restrict__ ei,
                                                          int* __restrict__ cursor,
                                                          int* __restrict__ elist) {
    constexpr int KPAD = 40;
    __shared__ ushort_t As[128 * KPAD];
    __shared__ ushort_t Bs[128 * KPAD];
    const int tid = threadIdx.x;

    if (blockIdx.x >= 512) {                       // ---- scatter part
        int e = (blockIdx.x - 512) * 256 + tid;
        int2 sd = ((const int2*)ei)[e];
        int b = e >> 16;
        int gi = (b << 14) + sd.x;
        int gj = (b << 14) + sd.y;
        int slot = atomicAdd(&cursor[gi], 1);
        if (slot < 64) elist[gi * 64 + slot] = gj;
        return;
    }

    const int m0 = blockIdx.x * 128;
    const int wave = tid >> 6;
    const int lane = tid & 63;
    const int lr = lane & 15;
    const int lq = lane >> 4;

    f32x4 acc[2][8];
#pragma unroll
    for (int mt = 0; mt < 2; mt++)
#pragma unroll
        for (int nt = 0; nt < 8; nt++) { f32x4 z = {0.f,0.f,0.f,0.f}; acc[mt][nt] = z; }

    for (int k0 = 0; k0 < 128; k0 += 32) {
#pragma unroll
        for (int i = 0; i < 4; i++) {
            int lin = tid + i * 256;
            int m = lin >> 3;
            int kq = (lin & 7) * 4;
            float4 v = *(const float4*)(A0 + (size_t)(m0 + m) * 128 + k0 + kq);
            ushort4 w4;
            w4.x = f2bf(v.x); w4.y = f2bf(v.y); w4.z = f2bf(v.z); w4.w = f2bf(v.w);
            if (EMIT_BF16)
                *(ushort4*)(hbout + (size_t)(m0 + m) * 128 + k0 + kq) = w4;
            *(ushort4*)&As[m * KPAD + kq] = w4;
        }
#pragma unroll
        for (int i = 0; i < 2; i++) {
            int lin = tid + i * 256;
            int n = lin >> 2;
            int kq = (lin & 3) * 8;
            *(uint4*)&Bs[n * KPAD + kq] = *(const uint4*)(Wt + (size_t)n * 128 + k0 + kq);
        }
        __syncthreads();
        bf16x8 af[2], bfr[8];
#pragma unroll
        for (int mt = 0; mt < 2; mt++)
            af[mt] = *(const bf16x8*)&As[(wave * 32 + mt * 16 + lr) * KPAD + lq * 8];
#pragma unroll
        for (int nt = 0; nt < 8; nt++)
            bfr[nt] = *(const bf16x8*)&Bs[(nt * 16 + lr) * KPAD + lq * 8];
#pragma unroll
        for (int mt = 0; mt < 2; mt++)
#pragma unroll
            for (int nt = 0; nt < 8; nt++)
                acc[mt][nt] = __builtin_amdgcn_mfma_f32_16x16x32_bf16(af[mt], bfr[nt], acc[mt][nt], 0, 0, 0);
        __syncthreads();
    }
#pragma unroll
    for (int mt = 0; mt < 2; mt++)
#pragma unroll
        for (int nt = 0; nt < 8; nt++)
#pragma unroll
            for (int r = 0; r < 4; r++) {
                int row = m0 + wave * 32 + mt * 16 + lq * 4 + r;
                int col = nt * 16 + lr;
                outP[(size_t)row * 128 + col] = f2bf(acc[mt][nt][r]);
            }
}

// ---------------------------------------------------------------------------
// node kernel (r16 proven, 61 us): one wave per node, lane = feature,
// register prefetch of next edge's gathers.
// ---------------------------------------------------------------------------
__global__ __launch_bounds__(64, 4) void node_k(const float* __restrict__ x,
                                                const ushort_t* __restrict__ P,
                                                const int* __restrict__ cursor,
                                                const int* __restrict__ elist,
                                                const float* __restrict__ w1,
                                                const float* __restrict__ b1,
                                                const unsigned* __restrict__ w2h,
                                                const float* __restrict__ b2,
                                                const float* __restrict__ pxw,
                                                ushort_t* __restrict__ dh,
                                                float* __restrict__ outx) {
    const int n = blockIdx.x;
    const int lane = threadIdx.x;
    __shared__ __attribute__((aligned(16))) unsigned m_u[32];    // 64 halves
    ushort_t* mh = (ushort_t*)m_u;

    const float w1r = w1[256 * 64 + lane];       // dist2 row of pe_w1
    const float b2v = b2[lane];
    const float pxv = pxw[lane];
    const float Pib = bf2f(P[(size_t)n * 128 + lane]) + b1[lane];
    const float xi0 = x[n * 3 + 0];
    const float xi1 = x[n * 3 + 1];
    const float xi2 = x[n * 3 + 2];

    float dhacc = 0.0f;
    float dxp0 = 0.0f, dxp1 = 0.0f, dxp2 = 0.0f;
    const int dg = min(cursor[n], 64);
    const int base = n * 64;

    int gj0 = (dg > 0) ? elist[base] : 0;
    float Pj = bf2f(P[(size_t)gj0 * 128 + 64 + lane]);
    float xj0 = x[gj0 * 3 + 0];
    float xj1 = x[gj0 * 3 + 1];
    float xj2 = x[gj0 * 3 + 2];

    for (int t = 0; t < dg; t++) {
        int gjn = (t + 1 < dg) ? elist[base + t + 1] : 0;
        float Pjn = bf2f(P[(size_t)gjn * 128 + 64 + lane]);
        float xn0 = x[gjn * 3 + 0];
        float xn1 = x[gjn * 3 + 1];
        float xn2 = x[gjn * 3 + 2];

        float ddx = xi0 - xj0;
        float ddy = xi1 - xj1;
        float ddz = xi2 - xj2;
        float d2 = fmaxf(ddx * ddx + ddy * ddy + ddz * ddz, 1e-12f);
        float m = fast_silu(Pib + Pj + d2 * w1r);
        __builtin_amdgcn_wave_barrier();
        union { ushort_t s; _Float16 h; } mc;
        mc.h = (_Float16)m;
        mh[lane] = mc.s;
        __builtin_amdgcn_wave_barrier();
        float s0 = b2v, s1 = 0.0f, s2 = 0.0f, s3 = 0.0f;
#pragma unroll
        for (int q = 0; q < 8; q++) {
            uint4 mm = *(const uint4*)&m_u[q * 4];               // ds_read_b128 broadcast
            s0 = __builtin_amdgcn_fdot2(u2h2(mm.x), u2h2(w2h[(4 * q + 0) * 64 + lane]), s0, false);
            s1 = __builtin_amdgcn_fdot2(u2h2(mm.y), u2h2(w2h[(4 * q + 1) * 64 + lane]), s1, false);
            s2 = __builtin_amdgcn_fdot2(u2h2(mm.z), u2h2(w2h[(4 * q + 2) * 64 + lane]), s2, false);
            s3 = __builtin_amdgcn_fdot2(u2h2(mm.w), u2h2(w2h[(4 * q + 3) * 64 + lane]), s3, false);
        }
        __builtin_amdgcn_wave_barrier();
        float m2 = fast_silu((s0 + s1) + (s2 + s3));
        dhacc += m2;
        float c = m2 * pxv * fast_rcp(sqrtf(d2) + 1e-8f);
        dxp0 = fmaf(c, ddx, dxp0);
        dxp1 = fmaf(c, ddy, dxp1);
        dxp2 = fmaf(c, ddz, dxp2);

        Pj = Pjn; xj0 = xn0; xj1 = xn1; xj2 = xn2;
    }

    dh[(size_t)n * 64 + lane] = f2bf(dhacc);                 // coalesced

    for (int off = 32; off; off >>= 1) {
        dxp0 += __shfl_down(dxp0, off);
        dxp1 += __shfl_down(dxp1, off);
        dxp2 += __shfl_down(dxp2, off);
    }
    if (lane == 0) {
        outx[n * 3 + 0] = xi0 + dxp0;
        outx[n * 3 + 1] = xi1 + dxp1;
        outx[n * 3 + 2] = xi2 + dxp2;
    }
}

// ---------------------------------------------------------------------------
// Fast fused node MLP (USE_HB path): out_h = h + silu([hb|dh]@W1+b1)@W2+b2.
// A (hb/dh, bf16) and B (weights, L2-resident) read directly from global in
// MFMA fragment layout — no As/Bs staging, ZERO __syncthreads (Ts rows are
// per-wave-private: epilogue-1 writes rows wave*32..+31, phase-2 reads the
// same band). LDS = Ts only (34.8 KB) -> 3 blocks/CU.
// ---------------------------------------------------------------------------
__global__ __launch_bounds__(256, 3) void mlp_fast_k(const ushort_t* __restrict__ hb,
                                                     const ushort_t* __restrict__ dh,
                                                     const ushort_t* __restrict__ Wp1t,
                                                     const float* __restrict__ b1,
                                                     const ushort_t* __restrict__ Wp2t,
                                                     const float* __restrict__ b2,
                                                     float* __restrict__ outh) {
    constexpr int TPAD = 136;
    __shared__ ushort_t Ts[128 * TPAD];
    const int tid = threadIdx.x;
    const int m0 = blockIdx.x * 128;
    const int wave = tid >> 6;
    const int lane = tid & 63;
    const int lr = lane & 15;
    const int lq = lane >> 4;

    // ---- phase 1: t = silu([hb|dh] @ W1 + b1), K = 192, frags from global
    f32x4 acc[2][8];
#pragma unroll
    for (int mt = 0; mt < 2; mt++)
#pragma unroll
        for (int nt = 0; nt < 8; nt++) { f32x4 z = {0.f,0.f,0.f,0.f}; acc[mt][nt] = z; }

    for (int k0 = 0; k0 < 192; k0 += 32) {
        bf16x8 af[2], bfr[8];
#pragma unroll
        for (int mt = 0; mt < 2; mt++) {
            int row = m0 + wave * 32 + mt * 16 + lr;
            af[mt] = (k0 < 128)
                ? *(const bf16x8*)&hb[(size_t)row * 128 + k0 + lq * 8]
                : *(const bf16x8*)&dh[(size_t)row * 64 + (k0 - 128) + lq * 8];
        }
#pragma unroll
        for (int nt = 0; nt < 8; nt++)
            bfr[nt] = *(const bf16x8*)&Wp1t[(size_t)(nt * 16 + lr) * 192 + k0 + lq * 8];
#pragma unroll
        for (int mt = 0; mt < 2; mt++)
#pragma unroll
            for (int nt = 0; nt < 8; nt++)
                acc[mt][nt] = __builtin_amdgcn_mfma_f32_16x16x32_bf16(af[mt], bfr[nt], acc[mt][nt], 0, 0, 0);
    }
    // epilogue 1: silu -> Ts (per-wave row band, no cross-wave sharing)
#pragma unroll
    for (int mt = 0; mt < 2; mt++)
#pragma unroll
        for (int nt = 0; nt < 8; nt++)
#pragma unroll
            for (int r = 0; r < 4; r++) {
                int row = wave * 32 + mt * 16 + lq * 4 + r;
                int col = nt * 16 + lr;
                Ts[row * TPAD + col] = f2bf(fast_silu(acc[mt][nt][r] + b1[col]));
            }

    // ---- phase 2: out = t @ W2 + b2 + hb residual, K = 128
    f32x4 acc2[2][8];
#pragma unroll
    for (int mt = 0; mt < 2; mt++)
#pragma unroll
        for (int nt = 0; nt < 8; nt++) { f32x4 z = {0.f,0.f,0.f,0.f}; acc2[mt][nt] = z; }

    for (int k0 = 0; k0 < 128; k0 += 32) {
        bf16x8 af[2], bfr[8];
#pragma unroll
        for (int mt = 0; mt < 2; mt++)
            af[mt] = *(const bf16x8*)&Ts[(wave * 32 + mt * 16 + lr) * TPAD + k0 + lq * 8];
#pragma unroll
        for (int nt = 0; nt < 8; nt++)
            bfr[nt] = *(const bf16x8*)&Wp2t[(size_t)(nt * 16 + lr) * 128 + k0 + lq * 8];
#pragma unroll
        for (int mt = 0; mt < 2; mt++)
#pragma unroll
            for (int nt = 0; nt < 8; nt++)
                acc2[mt][nt] = __builtin_amdgcn_mfma_f32_16x16x32_bf16(af[mt], bfr[nt], acc2[mt][nt], 0, 0, 0);
    }
    // epilogue 2: + b2 + h residual (from hb)
#pragma unroll
    for (int mt = 0; mt < 2; mt++)
#pragma unroll
        for (int nt = 0; nt < 8; nt++)
#pragma unroll
            for (int r = 0; r < 4; r++) {
                int row = m0 + wave * 32 + mt * 16 + lq * 4 + r;
                int col = nt * 16 + lr;
                float v = acc2[mt][nt][r] + b2[col] + bf2f(hb[(size_t)row * 128 + col]);
                outh[(size_t)row * 128 + col] = v;
            }
}

// ---------------------------------------------------------------------------
// Fallback fused MLP (no-hb path) — unchanged staged version.
// ---------------------------------------------------------------------------
__global__ __launch_bounds__(256, 2) void mlp_fused_k(const float* __restrict__ h,
                                                      const ushort_t* __restrict__ dh,
                                                      const ushort_t* __restrict__ Wp1t,
                                                      const float* __restrict__ b1,
                                                      const ushort_t* __restrict__ Wp2t,
                                                      const float* __restrict__ b2,
                                                      float* __restrict__ outh) {
    constexpr int KPAD = 40, TPAD = 136;
    __shared__ ushort_t As[128 * KPAD];
    __shared__ ushort_t Bs[128 * KPAD];
    __shared__ ushort_t Ts[128 * TPAD];
    const int tid = threadIdx.x;
    const int m0 = blockIdx.x * 128;
    const int wave = tid >> 6;
    const int lane = tid & 63;
    const int lr = lane & 15;
    const int lq = lane >> 4;

    f32x4 acc[2][8];
#pragma unroll
    for (int mt = 0; mt < 2; mt++)
#pragma unroll
        for (int nt = 0; nt < 8; nt++) { f32x4 z = {0.f,0.f,0.f,0.f}; acc[mt][nt] = z; }

    for (int k0 = 0; k0 < 192; k0 += 32) {
#pragma unroll
        for (int i = 0; i < 4; i++) {
            int lin = tid + i * 256;
            int m = lin >> 3;
            int kq = (lin & 7) * 4;
            ushort4 w4;
            if (k0 >= 128) {
                w4 = *(const ushort4*)(dh + (size_t)(m0 + m) * 64 + (k0 - 128 + kq));
            } else {
                float4 v = *(const float4*)(h + (size_t)(m0 + m) * 128 + k0 + kq);
                w4.x = f2bf(v.x); w4.y = f2bf(v.y); w4.z = f2bf(v.z); w4.w = f2bf(v.w);
            }
            *(ushort4*)&As[m * KPAD + kq] = w4;
        }
#pragma unroll
        for (int i = 0; i < 2; i++) {
            int lin = tid + i * 256;
            int n = lin >> 2;
            int kq = (lin & 3) * 8;
            *(uint4*)&Bs[n * KPAD + kq] = *(const uint4*)(Wp1t + (size_t)n * 192 + k0 + kq);
        }
        __syncthreads();
        bf16x8 af[2], bfr[8];
#pragma unroll
        for (int mt = 0; mt < 2; mt++)
            af[mt] = *(const bf16x8*)&As[(wave * 32 + mt * 16 + lr) * KPAD + lq * 8];
#pragma unroll
        for (int nt = 0; nt < 8; nt++)
            bfr[nt] = *(const bf16x8*)&Bs[(nt * 16 + lr) * KPAD + lq * 8];
#pragma unroll
        for (int mt = 0; mt < 2; mt++)
#pragma unroll
            for (int nt = 0; nt < 8; nt++)
                acc[mt][nt] = __builtin_amdgcn_mfma_f32_16x16x32_bf16(af[mt], bfr[nt], acc[mt][nt], 0, 0, 0);
        __syncthreads();
    }
#pragma unroll
    for (int mt = 0; mt < 2; mt++)
#pragma unroll
        for (int nt = 0; nt < 8; nt++)
#pragma unroll
            for (int r = 0; r < 4; r++) {
                int row = wave * 32 + mt * 16 + lq * 4 + r;
                int col = nt * 16 + lr;
                Ts[row * TPAD + col] = f2bf(fast_silu(acc[mt][nt][r] + b1[col]));
            }
    __syncthreads();

    f32x4 acc2[2][8];
#pragma unroll
    for (int mt = 0; mt < 2; mt++)
#pragma unroll
        for (int nt = 0; nt < 8; nt++) { f32x4 z = {0.f,0.f,0.f,0.f}; acc2[mt][nt] = z; }

    for (int k0 = 0; k0 < 128; k0 += 32) {
#pragma unroll
        for (int i = 0; i < 2; i++) {
            int lin = tid + i * 256;
            int n = lin >> 2;
            int kq = (lin & 3) * 8;
            *(uint4*)&Bs[n * KPAD + kq] = *(const uint4*)(Wp2t + (size_t)n * 128 + k0 + kq);
        }
        __syncthreads();
        bf16x8 af[2], bfr[8];
#pragma unroll
        for (int mt = 0; mt < 2; mt++)
            af[mt] = *(const bf16x8*)&Ts[(wave * 32 + mt * 16 + lr) * TPAD + k0 + lq * 8];
#pragma unroll
        for (int nt = 0; nt < 8; nt++)
            bfr[nt] = *(const bf16x8*)&Bs[(nt * 16 + lr) * KPAD + lq * 8];
#pragma unroll
        for (int mt = 0; mt < 2; mt++)
#pragma unroll
            for (int nt = 0; nt < 8; nt++)
                acc2[mt][nt] = __builtin_amdgcn_mfma_f32_16x16x32_bf16(af[mt], bfr[nt], acc2[mt][nt], 0, 0, 0);
        __syncthreads();
    }
#pragma unroll
    for (int mt = 0; mt < 2; mt++)
#pragma unroll
        for (int nt = 0; nt < 8; nt++)
#pragma unroll
            for (int r = 0; r < 4; r++) {
                int row = m0 + wave * 32 + mt * 16 + lq * 4 + r;
                int col = nt * 16 + lr;
                float v = acc2[mt][nt][r] + b2[col] + h[(size_t)row * 128 + col];
                outh[(size_t)row * 128 + col] = v;
            }
}

// ---------------------------------------------------------------------------
extern "C" void kernel_launch(void* const* d_in, const int* in_sizes, int n_in,
                              void* d_out, int out_size, void* d_ws, size_t ws_size,
                              hipStream_t stream) {
    const float* x     = (const float*)d_in[0];
    const float* h     = (const float*)d_in[1];
    const int*   ei    = (const int*)d_in[2];
    const float* pe_w1 = (const float*)d_in[3];
    const float* pe_b1 = (const float*)d_in[4];
    const float* pe_w2 = (const float*)d_in[5];
    const float* pe_b2 = (const float*)d_in[6];
    const float* px_w  = (const float*)d_in[7];
    const float* ph_w1 = (const float*)d_in[8];
    const float* ph_b1 = (const float*)d_in[9];
    const float* ph_w2 = (const float*)d_in[10];
    const float* ph_b2 = (const float*)d_in[11];

    float* outx = (float*)d_out;                    // 4*16384*3
    float* outh = (float*)d_out + 196608;           // 4*16384*128

    // ws layout
    ushort_t* P    = (ushort_t*)d_ws;                     // 65536*128 bf16
    ushort_t* dh   = P + (size_t)65536 * 128;             // 65536*64 bf16
    int* cursor    = (int*)(dh + (size_t)65536 * 64);     // 65536 i32
    int* elist     = cursor + 65536;                      // 65536*64 i32 (16 MB)
    ushort_t* W1t  = (ushort_t*)(elist + (size_t)65536 * 64);  // 128*128 bf16
    ushort_t* Wp1t = W1t + 16384;                         // 128*192 bf16
    ushort_t* Wp2t = Wp1t + 24576;                        // 128*128 bf16
    unsigned* w2h  = (unsigned*)(Wp2t + 16384);           // 32*64 uint (in 16KB slot)
    ushort_t* hb   = (ushort_t*)(w2h + 4096);             // 65536*128 bf16 (16 MB)
    size_t need_hb = (size_t)((char*)(hb + (size_t)65536 * 128) - (char*)d_ws);
    const bool use_hb = ws_size >= need_hb;

    init_k<<<488, 256, 0, stream>>>(pe_w1, pe_w2, ph_w1, ph_w2,
                                    cursor, W1t, Wp1t, Wp2t, w2h);
    if (use_hb)
        pgemm_scatter_k<true><<<1536, 256, 0, stream>>>(h, W1t, P, hb,
                                                        ei, cursor, elist);
    else
        pgemm_scatter_k<false><<<1536, 256, 0, stream>>>(h, W1t, P, nullptr,
                                                         ei, cursor, elist);
    node_k<<<65536, 64, 0, stream>>>(x, P, cursor, elist,
                                     pe_w1, pe_b1, w2h, pe_b2, px_w,
                                     dh, outx);
    if (use_hb)
        mlp_fast_k<<<512, 256, 0, stream>>>(hb, dh, Wp1t, ph_b1,
                                            Wp2t, ph_b2, outh);
    else
        mlp_fused_k<<<512, 256, 0, stream>>>(h, dh, Wp1t, ph_b1,
                                             Wp2t, ph_b2, outh);
}

// Round 10
// 198.492 us; speedup vs baseline: 1.0159x; 1.0159x over previous
//
#include <hip/hip_runtime.h>

// EGNN layer, round 18: r16 base (193.9 us) with ONE change — node_k uses the
// r12 2-edge interleaved inner loop (w2h loads shared across the edge pair =
// 16 VMEM/edge vs 32, dual dot chains for ILP) at its ORIGINAL 1-wave/block
// shape with __launch_bounds__(64,4): VGPR cap 128, so the ~55-reg live set
// fits (r12's spill was the (256,8)=64-cap, not the algorithm).
// mlp/scatter/pgemm reverted to r16-proven forms (r17's global-fragment mlp
// regressed: uncoalesced 16-row fragment gathers, no B reuse).
// B=4, N=16384, E=65536, DH=128, DM=64.  NB = 65536 global nodes.

typedef unsigned short ushort_t;
typedef __attribute__((ext_vector_type(8))) short bf16x8;
typedef __attribute__((ext_vector_type(4))) float f32x4;
typedef _Float16 h2 __attribute__((ext_vector_type(2)));

__device__ __forceinline__ float fast_rcp(float v) { return __builtin_amdgcn_rcpf(v); }
__device__ __forceinline__ float fast_silu(float v) { return v * fast_rcp(1.0f + __expf(-v)); }
__device__ __forceinline__ ushort_t f2bf(float f) {
    unsigned u = __float_as_uint(f);
    u += 0x7fffu + ((u >> 16) & 1u);
    return (ushort_t)(u >> 16);
}
__device__ __forceinline__ float bf2f(ushort_t b) {
    return __uint_as_float(((unsigned)b) << 16);
}
__device__ __forceinline__ h2 u2h2(unsigned u) {
    union { unsigned u; h2 h; } v; v.u = u; return v.h;
}

// ---------------------------------------------------------------------------
// init: cursor=0 (65536) + weight transforms. 488*256 = 124928 threads exact.
//  W1t  bf16[128][128] : fused pe_w1 cols, k-contiguous
//  Wp1t bf16[128][192] : ph_w1^T
//  Wp2t bf16[128][128] : ph_w2^T
//  w2h  uint[32][64]   : w2h[k2*64+c] = half2(pe_w2[2k2][c], pe_w2[2k2+1][c])
// ---------------------------------------------------------------------------
__global__ __launch_bounds__(256) void init_k(const float* __restrict__ pe_w1,
                                              const float* __restrict__ pe_w2,
                                              const float* __restrict__ ph_w1,
                                              const float* __restrict__ ph_w2,
                                              int* __restrict__ cursor,
                                              ushort_t* __restrict__ W1t,
                                              ushort_t* __restrict__ Wp1t,
                                              ushort_t* __restrict__ Wp2t,
                                              unsigned* __restrict__ w2h) {
    int gg = blockIdx.x * 256 + threadIdx.x;
    if (gg < 65536) { cursor[gg] = 0; return; }
    int g = gg - 65536;
    if (g < 16384) {
        int c = g >> 7, k = g & 127;
        float v = (c < 64) ? pe_w1[k * 64 + c] : pe_w1[(128 + k) * 64 + (c - 64)];
        W1t[g] = f2bf(v);
    } else if (g < 40960) {
        int g2 = g - 16384;
        int n = g2 / 192, k = g2 - n * 192;
        Wp1t[g2] = f2bf(ph_w1[k * 128 + n]);
    } else if (g < 57344) {
        int g3 = g - 40960;
        int n = g3 >> 7, k = g3 & 127;
        Wp2t[g3] = f2bf(ph_w2[k * 128 + n]);
    } else if (g < 59392) {
        int g4 = g - 57344;
        int k2 = g4 >> 6, c = g4 & 63;
        union { unsigned u; _Float16 h[2]; } p;
        p.h[0] = (_Float16)pe_w2[(2 * k2) * 64 + c];
        p.h[1] = (_Float16)pe_w2[(2 * k2 + 1) * 64 + c];
        w2h[g4] = p.u;
    }
}

// ---------------------------------------------------------------------------
// scatter: elist[gi*64 + slot] = gj  (deg max ~20 << 64)
// ---------------------------------------------------------------------------
__global__ __launch_bounds__(256) void scatter_k(const int* __restrict__ ei,
                                                 int* __restrict__ cursor,
                                                 int* __restrict__ elist) {
    int e = blockIdx.x * 256 + threadIdx.x;
    int2 sd = ((const int2*)ei)[e];
    int b = e >> 16;
    int gi = (b << 14) + sd.x;
    int gj = (b << 14) + sd.y;
    int slot = atomicAdd(&cursor[gi], 1);
    if (slot < 64) elist[gi * 64 + slot] = gj;
}

// ---------------------------------------------------------------------------
// node kernel, round 18: one wave per node, lane = feature; 2-edge software
// pipeline (r12 arithmetic, proven correct) at __launch_bounds__(64,4) so the
// ~55-VGPR live set fits without spilling. w2h loads shared across the pair.
// ---------------------------------------------------------------------------
__global__ __launch_bounds__(64, 4) void node_k(const float* __restrict__ x,
                                                const ushort_t* __restrict__ P,
                                                const int* __restrict__ cursor,
                                                const int* __restrict__ elist,
                                                const float* __restrict__ w1,
                                                const float* __restrict__ b1,
                                                const unsigned* __restrict__ w2h,
                                                const float* __restrict__ b2,
                                                const float* __restrict__ pxw,
                                                ushort_t* __restrict__ dh,
                                                float* __restrict__ outx) {
    const int n = blockIdx.x;
    const int lane = threadIdx.x;
    __shared__ __attribute__((aligned(16))) unsigned m_u[2][32];   // 2 edge buffers
    ushort_t* mh0 = (ushort_t*)m_u[0];
    ushort_t* mh1 = (ushort_t*)m_u[1];

    const float w1r = w1[256 * 64 + lane];       // dist2 row of pe_w1
    const float b2v = b2[lane];
    const float pxv = pxw[lane];
    const float Pib = bf2f(P[(size_t)n * 128 + lane]) + b1[lane];
    const float xi0 = x[n * 3 + 0];
    const float xi1 = x[n * 3 + 1];
    const float xi2 = x[n * 3 + 2];

    float dhacc = 0.0f;
    float dxp0 = 0.0f, dxp1 = 0.0f, dxp2 = 0.0f;
    const int dg = min(cursor[n], 64);

    // coalesced preload of the whole adjacency row (one 256B load / wave)
    int gjv = 0;
    if (lane < dg) gjv = elist[n * 64 + lane];

    int t = 0;
    for (; t + 2 <= dg; t += 2) {
        const int gjA = __builtin_amdgcn_readlane(gjv, t);
        const int gjB = __builtin_amdgcn_readlane(gjv, t + 1);
        // --- layer 1, both edges (independent gathers overlap)
        float PjA = bf2f(P[(size_t)gjA * 128 + 64 + lane]);
        float PjB = bf2f(P[(size_t)gjB * 128 + 64 + lane]);
        float ax = xi0 - x[gjA * 3 + 0];
        float ay = xi1 - x[gjA * 3 + 1];
        float az = xi2 - x[gjA * 3 + 2];
        float bx = xi0 - x[gjB * 3 + 0];
        float by = xi1 - x[gjB * 3 + 1];
        float bz = xi2 - x[gjB * 3 + 2];
        float d2A = fmaxf(ax * ax + ay * ay + az * az, 1e-12f);
        float d2B = fmaxf(bx * bx + by * by + bz * bz, 1e-12f);
        float mA = fast_silu(Pib + PjA + d2A * w1r);
        float mB = fast_silu(Pib + PjB + d2B * w1r);
        union { ushort_t s; _Float16 h; } ca, cb;
        ca.h = (_Float16)mA;
        cb.h = (_Float16)mB;
        __builtin_amdgcn_wave_barrier();
        mh0[lane] = ca.s;
        mh1[lane] = cb.s;
        __builtin_amdgcn_wave_barrier();
        // --- layer 2: two interleaved dot chains, w2h loads shared (CSE)
        float a0 = b2v, a1 = 0.f, a2 = 0.f, a3 = 0.f;
        float e0 = b2v, e1 = 0.f, e2 = 0.f, e3 = 0.f;
#pragma unroll
        for (int q = 0; q < 8; q++) {
            uint4 mmA = *(const uint4*)&m_u[0][q * 4];
            uint4 mmB = *(const uint4*)&m_u[1][q * 4];
            h2 w0 = u2h2(w2h[(4 * q + 0) * 64 + lane]);
            h2 w1q = u2h2(w2h[(4 * q + 1) * 64 + lane]);
            h2 w2q = u2h2(w2h[(4 * q + 2) * 64 + lane]);
            h2 w3 = u2h2(w2h[(4 * q + 3) * 64 + lane]);
            a0 = __builtin_amdgcn_fdot2(u2h2(mmA.x), w0, a0, false);
            e0 = __builtin_amdgcn_fdot2(u2h2(mmB.x), w0, e0, false);
            a1 = __builtin_amdgcn_fdot2(u2h2(mmA.y), w1q, a1, false);
            e1 = __builtin_amdgcn_fdot2(u2h2(mmB.y), w1q, e1, false);
            a2 = __builtin_amdgcn_fdot2(u2h2(mmA.z), w2q, a2, false);
            e2 = __builtin_amdgcn_fdot2(u2h2(mmB.z), w2q, e2, false);
            a3 = __builtin_amdgcn_fdot2(u2h2(mmA.w), w3, a3, false);
            e3 = __builtin_amdgcn_fdot2(u2h2(mmB.w), w3, e3, false);
        }
        __builtin_amdgcn_wave_barrier();
        float m2A = fast_silu((a0 + a1) + (a2 + a3));
        float m2B = fast_silu((e0 + e1) + (e2 + e3));
        dhacc += m2A + m2B;
        float cA = m2A * pxv * fast_rcp(sqrtf(d2A) + 1e-8f);
        float cB = m2B * pxv * fast_rcp(sqrtf(d2B) + 1e-8f);
        dxp0 = fmaf(cA, ax, fmaf(cB, bx, dxp0));
        dxp1 = fmaf(cA, ay, fmaf(cB, by, dxp1));
        dxp2 = fmaf(cA, az, fmaf(cB, bz, dxp2));
    }
    if (t < dg) {                                 // odd-degree tail, buf0
        const int gj = __builtin_amdgcn_readlane(gjv, t);
        float Pj = bf2f(P[(size_t)gj * 128 + 64 + lane]);
        float ax = xi0 - x[gj * 3 + 0];
        float ay = xi1 - x[gj * 3 + 1];
        float az = xi2 - x[gj * 3 + 2];
        float d2 = fmaxf(ax * ax + ay * ay + az * az, 1e-12f);
        float m = fast_silu(Pib + Pj + d2 * w1r);
        union { ushort_t s; _Float16 h; } mc;
        mc.h = (_Float16)m;
        __builtin_amdgcn_wave_barrier();
        mh0[lane] = mc.s;
        __builtin_amdgcn_wave_barrier();
        float a0 = b2v, a1 = 0.f, a2 = 0.f, a3 = 0.f;
#pragma unroll
        for (int q = 0; q < 8; q++) {
            uint4 mm = *(const uint4*)&m_u[0][q * 4];
            a0 = __builtin_amdgcn_fdot2(u2h2(mm.x), u2h2(w2h[(4 * q + 0) * 64 + lane]), a0, false);
            a1 = __builtin_amdgcn_fdot2(u2h2(mm.y), u2h2(w2h[(4 * q + 1) * 64 + lane]), a1, false);
            a2 = __builtin_amdgcn_fdot2(u2h2(mm.z), u2h2(w2h[(4 * q + 2) * 64 + lane]), a2, false);
            a3 = __builtin_amdgcn_fdot2(u2h2(mm.w), u2h2(w2h[(4 * q + 3) * 64 + lane]), a3, false);
        }
        __builtin_amdgcn_wave_barrier();
        float m2 = fast_silu((a0 + a1) + (a2 + a3));
        dhacc += m2;
        float c = m2 * pxv * fast_rcp(sqrtf(d2) + 1e-8f);
        dxp0 = fmaf(c, ax, dxp0);
        dxp1 = fmaf(c, ay, dxp1);
        dxp2 = fmaf(c, az, dxp2);
    }

    dh[(size_t)n * 64 + lane] = f2bf(dhacc);                 // coalesced

    for (int off = 32; off; off >>= 1) {
        dxp0 += __shfl_down(dxp0, off);
        dxp1 += __shfl_down(dxp1, off);
        dxp2 += __shfl_down(dxp2, off);
    }
    if (lane == 0) {
        outx[n * 3 + 0] = xi0 + dxp0;
        outx[n * 3 + 1] = xi1 + dxp1;
        outx[n * 3 + 2] = xi2 + dxp2;
    }
}

// ---------------------------------------------------------------------------
// P-GEMM: P = h @ [W1_top|W1_mid] (bf16 out), optionally emits hb=bf16(h).
// 128x128 block, 4 waves, 2x8 mfma 16x16x32, KPAD=40.
// ---------------------------------------------------------------------------
template <bool EMIT_BF16>
__global__ __launch_bounds__(256, 2) void pgemm_k(const float* __restrict__ A0,
                                                  const ushort_t* __restrict__ Wt,
                                                  ushort_t* __restrict__ outP,
                                                  ushort_t* __restrict__ hbout) {
    constexpr int KPAD = 40;
    __shared__ ushort_t As[128 * KPAD];
    __shared__ ushort_t Bs[128 * KPAD];
    const int tid = threadIdx.x;
    const int m0 = blockIdx.x * 128;
    const int wave = tid >> 6;
    const int lane = tid & 63;
    const int lr = lane & 15;
    const int lq = lane >> 4;

    f32x4 acc[2][8];
#pragma unroll
    for (int mt = 0; mt < 2; mt++)
#pragma unroll
        for (int nt = 0; nt < 8; nt++) { f32x4 z = {0.f,0.f,0.f,0.f}; acc[mt][nt] = z; }

    for (int k0 = 0; k0 < 128; k0 += 32) {
#pragma unroll
        for (int i = 0; i < 4; i++) {
            int lin = tid + i * 256;
            int m = lin >> 3;
            int kq = (lin & 7) * 4;
            float4 v = *(const float4*)(A0 + (size_t)(m0 + m) * 128 + k0 + kq);
            ushort4 w4;
            w4.x = f2bf(v.x); w4.y = f2bf(v.y); w4.z = f2bf(v.z); w4.w = f2bf(v.w);
            if (EMIT_BF16)
                *(ushort4*)(hbout + (size_t)(m0 + m) * 128 + k0 + kq) = w4;
            *(ushort4*)&As[m * KPAD + kq] = w4;
        }
#pragma unroll
        for (int i = 0; i < 2; i++) {
            int lin = tid + i * 256;
            int n = lin >> 2;
            int kq = (lin & 3) * 8;
            *(uint4*)&Bs[n * KPAD + kq] = *(const uint4*)(Wt + (size_t)n * 128 + k0 + kq);
        }
        __syncthreads();
        bf16x8 af[2], bfr[8];
#pragma unroll
        for (int mt = 0; mt < 2; mt++)
            af[mt] = *(const bf16x8*)&As[(wave * 32 + mt * 16 + lr) * KPAD + lq * 8];
#pragma unroll
        for (int nt = 0; nt < 8; nt++)
            bfr[nt] = *(const bf16x8*)&Bs[(nt * 16 + lr) * KPAD + lq * 8];
#pragma unroll
        for (int mt = 0; mt < 2; mt++)
#pragma unroll
            for (int nt = 0; nt < 8; nt++)
                acc[mt][nt] = __builtin_amdgcn_mfma_f32_16x16x32_bf16(af[mt], bfr[nt], acc[mt][nt], 0, 0, 0);
        __syncthreads();
    }
#pragma unroll
    for (int mt = 0; mt < 2; mt++)
#pragma unroll
        for (int nt = 0; nt < 8; nt++)
#pragma unroll
            for (int r = 0; r < 4; r++) {
                int row = m0 + wave * 32 + mt * 16 + lq * 4 + r;
                int col = nt * 16 + lr;
                outP[(size_t)row * 128 + col] = f2bf(acc[mt][nt][r]);
            }
}

// ---------------------------------------------------------------------------
// Fused node MLP: out_h = h + silu([h|dh]@W1 + b1) @ W2 + b2.
// Phase 1: t(128x128) = silu([h|dh]@W1+b1) -> LDS (bf16, pad 136).
// Phase 2: out = t @ W2 + b2 + h, straight from LDS. No t round-trip to HBM.
// ---------------------------------------------------------------------------
template <bool USE_HB>
__global__ __launch_bounds__(256, 2) void mlp_fused_k(const float* __restrict__ h,
                                                      const ushort_t* __restrict__ hb,
                                                      const ushort_t* __restrict__ dh,
                                                      const ushort_t* __restrict__ Wp1t,
                                                      const float* __restrict__ b1,
                                                      const ushort_t* __restrict__ Wp2t,
                                                      const float* __restrict__ b2,
                                                      float* __restrict__ outh) {
    constexpr int KPAD = 40, TPAD = 136;
    __shared__ ushort_t As[128 * KPAD];
    __shared__ ushort_t Bs[128 * KPAD];
    __shared__ ushort_t Ts[128 * TPAD];
    const int tid = threadIdx.x;
    const int m0 = blockIdx.x * 128;
    const int wave = tid >> 6;
    const int lane = tid & 63;
    const int lr = lane & 15;
    const int lq = lane >> 4;

    f32x4 acc[2][8];
#pragma unroll
    for (int mt = 0; mt < 2; mt++)
#pragma unroll
        for (int nt = 0; nt < 8; nt++) { f32x4 z = {0.f,0.f,0.f,0.f}; acc[mt][nt] = z; }

    // ---- phase 1: t = silu([h|dh] @ W1 + b1), K = 192
    for (int k0 = 0; k0 < 192; k0 += 32) {
        if (USE_HB) {
#pragma unroll
            for (int i = 0; i < 2; i++) {
                int lin = tid + i * 256;
                int m = lin >> 2;
                int kq = (lin & 3) * 8;
                const ushort_t* src = (k0 >= 128)
                    ? dh + (size_t)(m0 + m) * 64 + (k0 - 128 + kq)
                    : hb + (size_t)(m0 + m) * 128 + k0 + kq;
                *(uint4*)&As[m * KPAD + kq] = *(const uint4*)src;
            }
        } else {
#pragma unroll
            for (int i = 0; i < 4; i++) {
                int lin = tid + i * 256;
                int m = lin >> 3;
                int kq = (lin & 7) * 4;
                ushort4 w4;
                if (k0 >= 128) {
                    w4 = *(const ushort4*)(dh + (size_t)(m0 + m) * 64 + (k0 - 128 + kq));
                } else {
                    float4 v = *(const float4*)(h + (size_t)(m0 + m) * 128 + k0 + kq);
                    w4.x = f2bf(v.x); w4.y = f2bf(v.y); w4.z = f2bf(v.z); w4.w = f2bf(v.w);
                }
                *(ushort4*)&As[m * KPAD + kq] = w4;
            }
        }
#pragma unroll
        for (int i = 0; i < 2; i++) {
            int lin = tid + i * 256;
            int n = lin >> 2;
            int kq = (lin & 3) * 8;
            *(uint4*)&Bs[n * KPAD + kq] = *(const uint4*)(Wp1t + (size_t)n * 192 + k0 + kq);
        }
        __syncthreads();
        bf16x8 af[2], bfr[8];
#pragma unroll
        for (int mt = 0; mt < 2; mt++)
            af[mt] = *(const bf16x8*)&As[(wave * 32 + mt * 16 + lr) * KPAD + lq * 8];
#pragma unroll
        for (int nt = 0; nt < 8; nt++)
            bfr[nt] = *(const bf16x8*)&Bs[(nt * 16 + lr) * KPAD + lq * 8];
#pragma unroll
        for (int mt = 0; mt < 2; mt++)
#pragma unroll
            for (int nt = 0; nt < 8; nt++)
                acc[mt][nt] = __builtin_amdgcn_mfma_f32_16x16x32_bf16(af[mt], bfr[nt], acc[mt][nt], 0, 0, 0);
        __syncthreads();
    }
    // epilogue 1: silu -> Ts (bf16)
#pragma unroll
    for (int mt = 0; mt < 2; mt++)
#pragma unroll
        for (int nt = 0; nt < 8; nt++)
#pragma unroll
            for (int r = 0; r < 4; r++) {
                int row = wave * 32 + mt * 16 + lq * 4 + r;
                int col = nt * 16 + lr;
                Ts[row * TPAD + col] = f2bf(fast_silu(acc[mt][nt][r] + b1[col]));
            }
    __syncthreads();

    // ---- phase 2: out = t @ W2 + b2 + h, K = 128, A from Ts
    f32x4 acc2[2][8];
#pragma unroll
    for (int mt = 0; mt < 2; mt++)
#pragma unroll
        for (int nt = 0; nt < 8; nt++) { f32x4 z = {0.f,0.f,0.f,0.f}; acc2[mt][nt] = z; }

    for (int k0 = 0; k0 < 128; k0 += 32) {
#pragma unroll
        for (int i = 0; i < 2; i++) {
            int lin = tid + i * 256;
            int n = lin >> 2;
            int kq = (lin & 3) * 8;
            *(uint4*)&Bs[n * KPAD + kq] = *(const uint4*)(Wp2t + (size_t)n * 128 + k0 + kq);
        }
        __syncthreads();
        bf16x8 af[2], bfr[8];
#pragma unroll
        for (int mt = 0; mt < 2; mt++)
            af[mt] = *(const bf16x8*)&Ts[(wave * 32 + mt * 16 + lr) * TPAD + k0 + lq * 8];
#pragma unroll
        for (int nt = 0; nt < 8; nt++)
            bfr[nt] = *(const bf16x8*)&Bs[(nt * 16 + lr) * KPAD + lq * 8];
#pragma unroll
        for (int mt = 0; mt < 2; mt++)
#pragma unroll
            for (int nt = 0; nt < 8; nt++)
                acc2[mt][nt] = __builtin_amdgcn_mfma_f32_16x16x32_bf16(af[mt], bfr[nt], acc2[mt][nt], 0, 0, 0);
        __syncthreads();
    }
    // epilogue 2: + b2 + h residual
#pragma unroll
    for (int mt = 0; mt < 2; mt++)
#pragma unroll
        for (int nt = 0; nt < 8; nt++)
#pragma unroll
            for (int r = 0; r < 4; r++) {
                int row = m0 + wave * 32 + mt * 16 + lq * 4 + r;
                int col = nt * 16 + lr;
                float v = acc2[mt][nt][r] + b2[col];
                if (USE_HB) v += bf2f(hb[(size_t)row * 128 + col]);
                else        v += h[(size_t)row * 128 + col];
                outh[(size_t)row * 128 + col] = v;
            }
}

// ---------------------------------------------------------------------------
extern "C" void kernel_launch(void* const* d_in, const int* in_sizes, int n_in,
                              void* d_out, int out_size, void* d_ws, size_t ws_size,
                              hipStream_t stream) {
    const float* x     = (const float*)d_in[0];
    const float* h     = (const float*)d_in[1];
    const int*   ei    = (const int*)d_in[2];
    const float* pe_w1 = (const float*)d_in[3];
    const float* pe_b1 = (const float*)d_in[4];
    const float* pe_w2 = (const float*)d_in[5];
    const float* pe_b2 = (const float*)d_in[6];
    const float* px_w  = (const float*)d_in[7];
    const float* ph_w1 = (const float*)d_in[8];
    const float* ph_b1 = (const float*)d_in[9];
    const float* ph_w2 = (const float*)d_in[10];
    const float* ph_b2 = (const float*)d_in[11];

    float* outx = (float*)d_out;                    // 4*16384*3
    float* outh = (float*)d_out + 196608;           // 4*16384*128

    // ws layout
    ushort_t* P    = (ushort_t*)d_ws;                     // 65536*128 bf16
    ushort_t* dh   = P + (size_t)65536 * 128;             // 65536*64 bf16
    int* cursor    = (int*)(dh + (size_t)65536 * 64);     // 65536 i32
    int* elist     = cursor + 65536;                      // 65536*64 i32 (16 MB)
    ushort_t* W1t  = (ushort_t*)(elist + (size_t)65536 * 64);  // 128*128 bf16
    ushort_t* Wp1t = W1t + 16384;                         // 128*192 bf16
    ushort_t* Wp2t = Wp1t + 24576;                        // 128*128 bf16
    unsigned* w2h  = (unsigned*)(Wp2t + 16384);           // 32*64 uint (in 16KB slot)
    ushort_t* hb   = (ushort_t*)(w2h + 4096);             // 65536*128 bf16 (16 MB)
    size_t need_hb = (size_t)((char*)(hb + (size_t)65536 * 128) - (char*)d_ws);
    const bool use_hb = ws_size >= need_hb;

    init_k<<<488, 256, 0, stream>>>(pe_w1, pe_w2, ph_w1, ph_w2,
                                    cursor, W1t, Wp1t, Wp2t, w2h);
    if (use_hb)
        pgemm_k<true><<<512, 256, 0, stream>>>(h, W1t, P, hb);
    else
        pgemm_k<false><<<512, 256, 0, stream>>>(h, W1t, P, nullptr);
    scatter_k<<<1024, 256, 0, stream>>>(ei, cursor, elist);
    node_k<<<65536, 64, 0, stream>>>(x, P, cursor, elist,
                                     pe_w1, pe_b1, w2h, pe_b2, px_w,
                                     dh, outx);
    if (use_hb)
        mlp_fused_k<true><<<512, 256, 0, stream>>>(h, hb, dh, Wp1t, ph_b1,
                                                   Wp2t, ph_b2, outh);
    else
        mlp_fused_k<false><<<512, 256, 0, stream>>>(h, nullptr, dh, Wp1t, ph_b1,
                                                    Wp2t, ph_b2, outh);
}

// Round 11
// 190.639 us; speedup vs baseline: 1.0578x; 1.0412x over previous
//
#include <hip/hip_runtime.h>

// EGNN layer, round 19: r16 base (193.9 us, best) + ONE proven change from
// r17 unbundled: scatter fused into the pgemm launch (blocks >=512 run the
// scatter; data-independent of the GEMM blocks). Removes one launch gap and
// overlaps ~10 us of atomic-bound scatter under pgemm's MFMA work.
// node_k = r16 proven (61 us floor for this family: prefetch/2-edge/4-edge/
// packing all tested worse or spilled). mlp = r16 staged (r17's
// global-fragment version regressed).
// B=4, N=16384, E=65536, DH=128, DM=64.  NB = 65536 global nodes.

typedef unsigned short ushort_t;
typedef __attribute__((ext_vector_type(8))) short bf16x8;
typedef __attribute__((ext_vector_type(4))) float f32x4;
typedef _Float16 h2 __attribute__((ext_vector_type(2)));

__device__ __forceinline__ float fast_rcp(float v) { return __builtin_amdgcn_rcpf(v); }
__device__ __forceinline__ float fast_silu(float v) { return v * fast_rcp(1.0f + __expf(-v)); }
__device__ __forceinline__ ushort_t f2bf(float f) {
    unsigned u = __float_as_uint(f);
    u += 0x7fffu + ((u >> 16) & 1u);
    return (ushort_t)(u >> 16);
}
__device__ __forceinline__ float bf2f(ushort_t b) {
    return __uint_as_float(((unsigned)b) << 16);
}
__device__ __forceinline__ h2 u2h2(unsigned u) {
    union { unsigned u; h2 h; } v; v.u = u; return v.h;
}

// ---------------------------------------------------------------------------
// init: cursor=0 (65536) + weight transforms. 488*256 = 124928 threads exact.
//  W1t  bf16[128][128] : fused pe_w1 cols, k-contiguous
//  Wp1t bf16[128][192] : ph_w1^T
//  Wp2t bf16[128][128] : ph_w2^T
//  w2h  uint[32][64]   : w2h[k2*64+c] = half2(pe_w2[2k2][c], pe_w2[2k2+1][c])
// ---------------------------------------------------------------------------
__global__ __launch_bounds__(256) void init_k(const float* __restrict__ pe_w1,
                                              const float* __restrict__ pe_w2,
                                              const float* __restrict__ ph_w1,
                                              const float* __restrict__ ph_w2,
                                              int* __restrict__ cursor,
                                              ushort_t* __restrict__ W1t,
                                              ushort_t* __restrict__ Wp1t,
                                              ushort_t* __restrict__ Wp2t,
                                              unsigned* __restrict__ w2h) {
    int gg = blockIdx.x * 256 + threadIdx.x;
    if (gg < 65536) { cursor[gg] = 0; return; }
    int g = gg - 65536;
    if (g < 16384) {
        int c = g >> 7, k = g & 127;
        float v = (c < 64) ? pe_w1[k * 64 + c] : pe_w1[(128 + k) * 64 + (c - 64)];
        W1t[g] = f2bf(v);
    } else if (g < 40960) {
        int g2 = g - 16384;
        int n = g2 / 192, k = g2 - n * 192;
        Wp1t[g2] = f2bf(ph_w1[k * 128 + n]);
    } else if (g < 57344) {
        int g3 = g - 40960;
        int n = g3 >> 7, k = g3 & 127;
        Wp2t[g3] = f2bf(ph_w2[k * 128 + n]);
    } else if (g < 59392) {
        int g4 = g - 57344;
        int k2 = g4 >> 6, c = g4 & 63;
        union { unsigned u; _Float16 h[2]; } p;
        p.h[0] = (_Float16)pe_w2[(2 * k2) * 64 + c];
        p.h[1] = (_Float16)pe_w2[(2 * k2 + 1) * 64 + c];
        w2h[g4] = p.u;
    }
}

// ---------------------------------------------------------------------------
// pgemm (blocks 0..511) + scatter (blocks 512..1535), fused launch.
// pgemm: P = h @ [W1_top|W1_mid] (bf16 out), emits hb=bf16(h) when EMIT.
// scatter: elist[gi*64 + slot] = gj (independent of pgemm; overlaps).
// ---------------------------------------------------------------------------
template <bool EMIT_BF16>
__global__ __launch_bounds__(256, 2) void pgemm_scatter_k(const float* __restrict__ A0,
                                                          const ushort_t* __restrict__ Wt,
                                                          ushort_t* __restrict__ outP,
                                                          ushort_t* __restrict__ hbout,
                                                          const int* __restrict__ ei,
                                                          int* __restrict__ cursor,
                                                          int* __restrict__ elist) {
    constexpr int KPAD = 40;
    __shared__ ushort_t As[128 * KPAD];
    __shared__ ushort_t Bs[128 * KPAD];
    const int tid = threadIdx.x;

    if (blockIdx.x >= 512) {                       // ---- scatter part
        int e = (blockIdx.x - 512) * 256 + tid;
        int2 sd = ((const int2*)ei)[e];
        int b = e >> 16;
        int gi = (b << 14) + sd.x;
        int gj = (b << 14) + sd.y;
        int slot = atomicAdd(&cursor[gi], 1);
        if (slot < 64) elist[gi * 64 + slot] = gj;
        return;
    }

    const int m0 = blockIdx.x * 128;
    const int wave = tid >> 6;
    const int lane = tid & 63;
    const int lr = lane & 15;
    const int lq = lane >> 4;

    f32x4 acc[2][8];
#pragma unroll
    for (int mt = 0; mt < 2; mt++)
#pragma unroll
        for (int nt = 0; nt < 8; nt++) { f32x4 z = {0.f,0.f,0.f,0.f}; acc[mt][nt] = z; }

    for (int k0 = 0; k0 < 128; k0 += 32) {
#pragma unroll
        for (int i = 0; i < 4; i++) {
            int lin = tid + i * 256;
            int m = lin >> 3;
            int kq = (lin & 7) * 4;
            float4 v = *(const float4*)(A0 + (size_t)(m0 + m) * 128 + k0 + kq);
            ushort4 w4;
            w4.x = f2bf(v.x); w4.y = f2bf(v.y); w4.z = f2bf(v.z); w4.w = f2bf(v.w);
            if (EMIT_BF16)
                *(ushort4*)(hbout + (size_t)(m0 + m) * 128 + k0 + kq) = w4;
            *(ushort4*)&As[m * KPAD + kq] = w4;
        }
#pragma unroll
        for (int i = 0; i < 2; i++) {
            int lin = tid + i * 256;
            int n = lin >> 2;
            int kq = (lin & 3) * 8;
            *(uint4*)&Bs[n * KPAD + kq] = *(const uint4*)(Wt + (size_t)n * 128 + k0 + kq);
        }
        __syncthreads();
        bf16x8 af[2], bfr[8];
#pragma unroll
        for (int mt = 0; mt < 2; mt++)
            af[mt] = *(const bf16x8*)&As[(wave * 32 + mt * 16 + lr) * KPAD + lq * 8];
#pragma unroll
        for (int nt = 0; nt < 8; nt++)
            bfr[nt] = *(const bf16x8*)&Bs[(nt * 16 + lr) * KPAD + lq * 8];
#pragma unroll
        for (int mt = 0; mt < 2; mt++)
#pragma unroll
            for (int nt = 0; nt < 8; nt++)
                acc[mt][nt] = __builtin_amdgcn_mfma_f32_16x16x32_bf16(af[mt], bfr[nt], acc[mt][nt], 0, 0, 0);
        __syncthreads();
    }
#pragma unroll
    for (int mt = 0; mt < 2; mt++)
#pragma unroll
        for (int nt = 0; nt < 8; nt++)
#pragma unroll
            for (int r = 0; r < 4; r++) {
                int row = m0 + wave * 32 + mt * 16 + lq * 4 + r;
                int col = nt * 16 + lr;
                outP[(size_t)row * 128 + col] = f2bf(acc[mt][nt][r]);
            }
}

// ---------------------------------------------------------------------------
// node kernel (r16 proven, 61 us): one wave per node, lane = feature,
// register prefetch of next edge's gathers.
// ---------------------------------------------------------------------------
__global__ __launch_bounds__(64, 4) void node_k(const float* __restrict__ x,
                                                const ushort_t* __restrict__ P,
                                                const int* __restrict__ cursor,
                                                const int* __restrict__ elist,
                                                const float* __restrict__ w1,
                                                const float* __restrict__ b1,
                                                const unsigned* __restrict__ w2h,
                                                const float* __restrict__ b2,
                                                const float* __restrict__ pxw,
                                                ushort_t* __restrict__ dh,
                                                float* __restrict__ outx) {
    const int n = blockIdx.x;
    const int lane = threadIdx.x;
    __shared__ __attribute__((aligned(16))) unsigned m_u[32];    // 64 halves
    ushort_t* mh = (ushort_t*)m_u;

    const float w1r = w1[256 * 64 + lane];       // dist2 row of pe_w1
    const float b2v = b2[lane];
    const float pxv = pxw[lane];
    const float Pib = bf2f(P[(size_t)n * 128 + lane]) + b1[lane];
    const float xi0 = x[n * 3 + 0];
    const float xi1 = x[n * 3 + 1];
    const float xi2 = x[n * 3 + 2];

    float dhacc = 0.0f;
    float dxp0 = 0.0f, dxp1 = 0.0f, dxp2 = 0.0f;
    const int dg = min(cursor[n], 64);
    const int base = n * 64;

    int gj0 = (dg > 0) ? elist[base] : 0;
    float Pj = bf2f(P[(size_t)gj0 * 128 + 64 + lane]);
    float xj0 = x[gj0 * 3 + 0];
    float xj1 = x[gj0 * 3 + 1];
    float xj2 = x[gj0 * 3 + 2];

    for (int t = 0; t < dg; t++) {
        int gjn = (t + 1 < dg) ? elist[base + t + 1] : 0;
        float Pjn = bf2f(P[(size_t)gjn * 128 + 64 + lane]);
        float xn0 = x[gjn * 3 + 0];
        float xn1 = x[gjn * 3 + 1];
        float xn2 = x[gjn * 3 + 2];

        float ddx = xi0 - xj0;
        float ddy = xi1 - xj1;
        float ddz = xi2 - xj2;
        float d2 = fmaxf(ddx * ddx + ddy * ddy + ddz * ddz, 1e-12f);
        float m = fast_silu(Pib + Pj + d2 * w1r);
        __builtin_amdgcn_wave_barrier();
        union { ushort_t s; _Float16 h; } mc;
        mc.h = (_Float16)m;
        mh[lane] = mc.s;
        __builtin_amdgcn_wave_barrier();
        float s0 = b2v, s1 = 0.0f, s2 = 0.0f, s3 = 0.0f;
#pragma unroll
        for (int q = 0; q < 8; q++) {
            uint4 mm = *(const uint4*)&m_u[q * 4];               // ds_read_b128 broadcast
            s0 = __builtin_amdgcn_fdot2(u2h2(mm.x), u2h2(w2h[(4 * q + 0) * 64 + lane]), s0, false);
            s1 = __builtin_amdgcn_fdot2(u2h2(mm.y), u2h2(w2h[(4 * q + 1) * 64 + lane]), s1, false);
            s2 = __builtin_amdgcn_fdot2(u2h2(mm.z), u2h2(w2h[(4 * q + 2) * 64 + lane]), s2, false);
            s3 = __builtin_amdgcn_fdot2(u2h2(mm.w), u2h2(w2h[(4 * q + 3) * 64 + lane]), s3, false);
        }
        __builtin_amdgcn_wave_barrier();
        float m2 = fast_silu((s0 + s1) + (s2 + s3));
        dhacc += m2;
        float c = m2 * pxv * fast_rcp(sqrtf(d2) + 1e-8f);
        dxp0 = fmaf(c, ddx, dxp0);
        dxp1 = fmaf(c, ddy, dxp1);
        dxp2 = fmaf(c, ddz, dxp2);

        Pj = Pjn; xj0 = xn0; xj1 = xn1; xj2 = xn2;
    }

    dh[(size_t)n * 64 + lane] = f2bf(dhacc);                 // coalesced

    for (int off = 32; off; off >>= 1) {
        dxp0 += __shfl_down(dxp0, off);
        dxp1 += __shfl_down(dxp1, off);
        dxp2 += __shfl_down(dxp2, off);
    }
    if (lane == 0) {
        outx[n * 3 + 0] = xi0 + dxp0;
        outx[n * 3 + 1] = xi1 + dxp1;
        outx[n * 3 + 2] = xi2 + dxp2;
    }
}

// ---------------------------------------------------------------------------
// Fused node MLP: out_h = h + silu([h|dh]@W1 + b1) @ W2 + b2.
// Phase 1: t(128x128) = silu([h|dh]@W1+b1) -> LDS (bf16, pad 136).
// Phase 2: out = t @ W2 + b2 + h, straight from LDS. No t round-trip to HBM.
// ---------------------------------------------------------------------------
template <bool USE_HB>
__global__ __launch_bounds__(256, 2) void mlp_fused_k(const float* __restrict__ h,
                                                      const ushort_t* __restrict__ hb,
                                                      const ushort_t* __restrict__ dh,
                                                      const ushort_t* __restrict__ Wp1t,
                                                      const float* __restrict__ b1,
                                                      const ushort_t* __restrict__ Wp2t,
                                                      const float* __restrict__ b2,
                                                      float* __restrict__ outh) {
    constexpr int KPAD = 40, TPAD = 136;
    __shared__ ushort_t As[128 * KPAD];
    __shared__ ushort_t Bs[128 * KPAD];
    __shared__ ushort_t Ts[128 * TPAD];
    const int tid = threadIdx.x;
    const int m0 = blockIdx.x * 128;
    const int wave = tid >> 6;
    const int lane = tid & 63;
    const int lr = lane & 15;
    const int lq = lane >> 4;

    f32x4 acc[2][8];
#pragma unroll
    for (int mt = 0; mt < 2; mt++)
#pragma unroll
        for (int nt = 0; nt < 8; nt++) { f32x4 z = {0.f,0.f,0.f,0.f}; acc[mt][nt] = z; }

    // ---- phase 1: t = silu([h|dh] @ W1 + b1), K = 192
    for (int k0 = 0; k0 < 192; k0 += 32) {
        if (USE_HB) {
#pragma unroll
            for (int i = 0; i < 2; i++) {
                int lin = tid + i * 256;
                int m = lin >> 2;
                int kq = (lin & 3) * 8;
                const ushort_t* src = (k0 >= 128)
                    ? dh + (size_t)(m0 + m) * 64 + (k0 - 128 + kq)
                    : hb + (size_t)(m0 + m) * 128 + k0 + kq;
                *(uint4*)&As[m * KPAD + kq] = *(const uint4*)src;
            }
        } else {
#pragma unroll
            for (int i = 0; i < 4; i++) {
                int lin = tid + i * 256;
                int m = lin >> 3;
                int kq = (lin & 7) * 4;
                ushort4 w4;
                if (k0 >= 128) {
                    w4 = *(const ushort4*)(dh + (size_t)(m0 + m) * 64 + (k0 - 128 + kq));
                } else {
                    float4 v = *(const float4*)(h + (size_t)(m0 + m) * 128 + k0 + kq);
                    w4.x = f2bf(v.x); w4.y = f2bf(v.y); w4.z = f2bf(v.z); w4.w = f2bf(v.w);
                }
                *(ushort4*)&As[m * KPAD + kq] = w4;
            }
        }
#pragma unroll
        for (int i = 0; i < 2; i++) {
            int lin = tid + i * 256;
            int n = lin >> 2;
            int kq = (lin & 3) * 8;
            *(uint4*)&Bs[n * KPAD + kq] = *(const uint4*)(Wp1t + (size_t)n * 192 + k0 + kq);
        }
        __syncthreads();
        bf16x8 af[2], bfr[8];
#pragma unroll
        for (int mt = 0; mt < 2; mt++)
            af[mt] = *(const bf16x8*)&As[(wave * 32 + mt * 16 + lr) * KPAD + lq * 8];
#pragma unroll
        for (int nt = 0; nt < 8; nt++)
            bfr[nt] = *(const bf16x8*)&Bs[(nt * 16 + lr) * KPAD + lq * 8];
#pragma unroll
        for (int mt = 0; mt < 2; mt++)
#pragma unroll
            for (int nt = 0; nt < 8; nt++)
                acc[mt][nt] = __builtin_amdgcn_mfma_f32_16x16x32_bf16(af[mt], bfr[nt], acc[mt][nt], 0, 0, 0);
        __syncthreads();
    }
    // epilogue 1: silu -> Ts (bf16)
#pragma unroll
    for (int mt = 0; mt < 2; mt++)
#pragma unroll
        for (int nt = 0; nt < 8; nt++)
#pragma unroll
            for (int r = 0; r < 4; r++) {
                int row = wave * 32 + mt * 16 + lq * 4 + r;
                int col = nt * 16 + lr;
                Ts[row * TPAD + col] = f2bf(fast_silu(acc[mt][nt][r] + b1[col]));
            }
    __syncthreads();

    // ---- phase 2: out = t @ W2 + b2 + h, K = 128, A from Ts
    f32x4 acc2[2][8];
#pragma unroll
    for (int mt = 0; mt < 2; mt++)
#pragma unroll
        for (int nt = 0; nt < 8; nt++) { f32x4 z = {0.f,0.f,0.f,0.f}; acc2[mt][nt] = z; }

    for (int k0 = 0; k0 < 128; k0 += 32) {
#pragma unroll
        for (int i = 0; i < 2; i++) {
            int lin = tid + i * 256;
            int n = lin >> 2;
            int kq = (lin & 3) * 8;
            *(uint4*)&Bs[n * KPAD + kq] = *(const uint4*)(Wp2t + (size_t)n * 128 + k0 + kq);
        }
        __syncthreads();
        bf16x8 af[2], bfr[8];
#pragma unroll
        for (int mt = 0; mt < 2; mt++)
            af[mt] = *(const bf16x8*)&Ts[(wave * 32 + mt * 16 + lr) * TPAD + k0 + lq * 8];
#pragma unroll
        for (int nt = 0; nt < 8; nt++)
            bfr[nt] = *(const bf16x8*)&Bs[(nt * 16 + lr) * KPAD + lq * 8];
#pragma unroll
        for (int mt = 0; mt < 2; mt++)
#pragma unroll
            for (int nt = 0; nt < 8; nt++)
                acc2[mt][nt] = __builtin_amdgcn_mfma_f32_16x16x32_bf16(af[mt], bfr[nt], acc2[mt][nt], 0, 0, 0);
        __syncthreads();
    }
    // epilogue 2: + b2 + h residual
#pragma unroll
    for (int mt = 0; mt < 2; mt++)
#pragma unroll
        for (int nt = 0; nt < 8; nt++)
#pragma unroll
            for (int r = 0; r < 4; r++) {
                int row = m0 + wave * 32 + mt * 16 + lq * 4 + r;
                int col = nt * 16 + lr;
                float v = acc2[mt][nt][r] + b2[col];
                if (USE_HB) v += bf2f(hb[(size_t)row * 128 + col]);
                else        v += h[(size_t)row * 128 + col];
                outh[(size_t)row * 128 + col] = v;
            }
}

// ---------------------------------------------------------------------------
extern "C" void kernel_launch(void* const* d_in, const int* in_sizes, int n_in,
                              void* d_out, int out_size, void* d_ws, size_t ws_size,
                              hipStream_t stream) {
    const float* x     = (const float*)d_in[0];
    const float* h     = (const float*)d_in[1];
    const int*   ei    = (const int*)d_in[2];
    const float* pe_w1 = (const float*)d_in[3];
    const float* pe_b1 = (const float*)d_in[4];
    const float* pe_w2 = (const float*)d_in[5];
    const float* pe_b2 = (const float*)d_in[6];
    const float* px_w  = (const float*)d_in[7];
    const float* ph_w1 = (const float*)d_in[8];
    const float* ph_b1 = (const float*)d_in[9];
    const float* ph_w2 = (const float*)d_in[10];
    const float* ph_b2 = (const float*)d_in[11];

    float* outx = (float*)d_out;                    // 4*16384*3
    float* outh = (float*)d_out + 196608;           // 4*16384*128

    // ws layout
    ushort_t* P    = (ushort_t*)d_ws;                     // 65536*128 bf16
    ushort_t* dh   = P + (size_t)65536 * 128;             // 65536*64 bf16
    int* cursor    = (int*)(dh + (size_t)65536 * 64);     // 65536 i32
    int* elist     = cursor + 65536;                      // 65536*64 i32 (16 MB)
    ushort_t* W1t  = (ushort_t*)(elist + (size_t)65536 * 64);  // 128*128 bf16
    ushort_t* Wp1t = W1t + 16384;                         // 128*192 bf16
    ushort_t* Wp2t = Wp1t + 24576;                        // 128*128 bf16
    unsigned* w2h  = (unsigned*)(Wp2t + 16384);           // 32*64 uint (in 16KB slot)
    ushort_t* hb   = (ushort_t*)(w2h + 4096);             // 65536*128 bf16 (16 MB)
    size_t need_hb = (size_t)((char*)(hb + (size_t)65536 * 128) - (char*)d_ws);
    const bool use_hb = ws_size >= need_hb;

    init_k<<<488, 256, 0, stream>>>(pe_w1, pe_w2, ph_w1, ph_w2,
                                    cursor, W1t, Wp1t, Wp2t, w2h);
    if (use_hb)
        pgemm_scatter_k<true><<<1536, 256, 0, stream>>>(h, W1t, P, hb,
                                                        ei, cursor, elist);
    else
        pgemm_scatter_k<false><<<1536, 256, 0, stream>>>(h, W1t, P, nullptr,
                                                         ei, cursor, elist);
    node_k<<<65536, 64, 0, stream>>>(x, P, cursor, elist,
                                     pe_w1, pe_b1, w2h, pe_b2, px_w,
                                     dh, outx);
    if (use_hb)
        mlp_fused_k<true><<<512, 256, 0, stream>>>(h, hb, dh, Wp1t, ph_b1,
                                                   Wp2t, ph_b2, outh);
    else
        mlp_fused_k<false><<<512, 256, 0, stream>>>(h, nullptr, dh, Wp1t, ph_b1,
                                                    Wp2t, ph_b2, outh);
}